// Round 1
// baseline (193.705 us; speedup 1.0000x reference)
//
#include <hip/hip_runtime.h>

#define N_NODES 100000
#define NUM_SAMPLE 25
#define FEAT_DIM 128

// One 32-lane group per output node; lane l owns float4 chunk l of the 128-dim row.
// Each neighbor-row read is 32 lanes x 16 B = 512 B fully coalesced.
__global__ __launch_bounds__(256) void MeanAggregator_kernel(
    const float* __restrict__ feat,
    const int* __restrict__ idx,
    float* __restrict__ out)
{
    const int gid   = blockIdx.x * blockDim.x + threadIdx.x;
    const int node  = gid >> 5;          // 32 lanes per node
    const int lane  = gid & 31;
    if (node >= N_NODES) return;

    const int* __restrict__ row_idx = idx + node * NUM_SAMPLE;

    float4 acc = make_float4(0.f, 0.f, 0.f, 0.f);

    #pragma unroll 5
    for (int s = 0; s < NUM_SAMPLE; ++s) {
        const int r = row_idx[s];
        const float4* __restrict__ src =
            reinterpret_cast<const float4*>(feat + (size_t)r * FEAT_DIM);
        float4 v = src[lane];
        acc.x += v.x; acc.y += v.y; acc.z += v.z; acc.w += v.w;
    }

    const float inv = 1.0f / (float)NUM_SAMPLE;
    float4 o = make_float4(acc.x * inv, acc.y * inv, acc.z * inv, acc.w * inv);
    reinterpret_cast<float4*>(out + (size_t)node * FEAT_DIM)[lane] = o;
}

extern "C" void kernel_launch(void* const* d_in, const int* in_sizes, int n_in,
                              void* d_out, int out_size, void* d_ws, size_t ws_size,
                              hipStream_t stream) {
    const float* feat = (const float*)d_in[0];
    const int*   idx  = (const int*)d_in[1];
    float*       out  = (float*)d_out;

    const int total_threads = N_NODES * 32;
    const int block = 256;
    const int grid  = (total_threads + block - 1) / block;  // 12500

    MeanAggregator_kernel<<<grid, block, 0, stream>>>(feat, idx, out);
}